// Round 3
// baseline (5157.033 us; speedup 1.0000x reference)
//
#include <hip/hip_runtime.h>
#include <hip/hip_bf16.h>
#include <math.h>

#define SEQ    2048
#define DIMN   1024
#define NHEAD  16
#define HDIM   64
#define BATCH  2
#define ROWS   (BATCH*SEQ)      // 4096
#define HIDDEN 2816
#define FCHUNK 512              // FFN row-chunk

// ---------------- t = silu(adafm_input) @ proj_w + proj_b ----------------
__global__ void k_time(const float* __restrict__ ada, const float* __restrict__ pw,
                       const float* __restrict__ pb, float* __restrict__ t){
  int b = blockIdx.x >> 9, o = blockIdx.x & 511, lane = threadIdx.x;
  float acc = 0.f;
  for(int i = lane; i < DIMN; i += 64){
    float a = ada[b*DIMN + i];
    float s = a / (1.f + expf(-a));
    acc += s * pw[i*512 + o];
  }
  for(int off = 32; off; off >>= 1) acc += __shfl_down(acc, off);
  if(lane == 0) t[b*512 + o] = acc + pb[o];
}

// ---------------- g[which][b][n] = (1/256) sum_k F[k] cos(2*pi*k*n/256) ----------------
__global__ void k_g(const float* __restrict__ t, float* __restrict__ g){
  int which = blockIdx.x >> 1, b = blockIdx.x & 1, n = threadIdx.x;
  const float C = 6.283185307179586f / 256.f;
  float acc = 0.f;
  for(int k = 0; k < 256; k++){
    float f = t[b*512 + which*256 + k];
    acc += f * cosf(C * (float)((k*n) & 255));
  }
  g[which*512 + b*256 + n] = acc * (1.f/256.f);
}

// ---------------- per-patch circular convolution (fp32) ----------------
__global__ void k_modulate(const float* __restrict__ src, const float* __restrict__ g,
                           float* __restrict__ dst){
  __shared__ float v[256];
  __shared__ float gd[512];
  int j = blockIdx.x, i = blockIdx.y, b = blockIdx.z, n = threadIdx.x;
  int r = n >> 4, c = n & 15;
  size_t off = (size_t)b*SEQ*DIMN + (size_t)(i*16 + r)*DIMN + j*16 + c;
  v[n] = src[off];
  float gv = g[b*256 + n];
  gd[n] = gv; gd[n + 256] = gv;
  __syncthreads();
  float acc = 0.f;
  #pragma unroll 8
  for(int m = 0; m < 256; m++) acc += v[m] * gd[n + 256 - m];
  dst[off] = acc;
}

// ---------------- C(MxN) = A(MxK) @ W(KxN), all fp32 ----------------
// 64x64 tile, block 256 (16x16), 4x4 per thread, K-chunk 16.
__global__ __launch_bounds__(256) void k_gemm(const float* __restrict__ A,
        const float* __restrict__ W, float* __restrict__ C, int M, int N, int K){
  __shared__ float As[16][64];   // [k][m]
  __shared__ float Bs[16][64];   // [k][n]
  int tid = threadIdx.x;
  int tx = tid & 15, ty = tid >> 4;
  int row0 = blockIdx.y*64, col0 = blockIdx.x*64;
  int am = tid >> 2, ak = (tid & 3)*4;
  int wk = tid >> 4, wn = (tid & 15)*4;
  float acc[4][4] = {};
  for(int kk = 0; kk < K; kk += 16){
    float4 av = *(const float4*)(A + (size_t)(row0 + am)*K + kk + ak);
    As[ak+0][am] = av.x; As[ak+1][am] = av.y; As[ak+2][am] = av.z; As[ak+3][am] = av.w;
    float4 wv = *(const float4*)(W + (size_t)(kk + wk)*N + col0 + wn);
    Bs[wk][wn+0] = wv.x; Bs[wk][wn+1] = wv.y; Bs[wk][wn+2] = wv.z; Bs[wk][wn+3] = wv.w;
    __syncthreads();
    #pragma unroll
    for(int k = 0; k < 16; k++){
      float4 a = *(const float4*)&As[k][ty*4];
      float4 b = *(const float4*)&Bs[k][tx*4];
      acc[0][0] += a.x*b.x; acc[0][1] += a.x*b.y; acc[0][2] += a.x*b.z; acc[0][3] += a.x*b.w;
      acc[1][0] += a.y*b.x; acc[1][1] += a.y*b.y; acc[1][2] += a.y*b.z; acc[1][3] += a.y*b.w;
      acc[2][0] += a.z*b.x; acc[2][1] += a.z*b.y; acc[2][2] += a.z*b.z; acc[2][3] += a.z*b.w;
      acc[3][0] += a.w*b.x; acc[3][1] += a.w*b.y; acc[3][2] += a.w*b.z; acc[3][3] += a.w*b.w;
    }
    __syncthreads();
  }
  for(int i2 = 0; i2 < 4; i2++){
    float4 o = make_float4(acc[i2][0], acc[i2][1], acc[i2][2], acc[i2][3]);
    *(float4*)(C + (size_t)(row0 + ty*4 + i2)*N + col0 + tx*4) = o;
  }
}

// ---------------- rotary + justnorm + sqk scale, IN PLACE on (B,S,DIM) ----------------
// grid (NH, SEQ, B), block 64 (one wave).
__global__ void k_qkvprep(float* __restrict__ xq, float* __restrict__ xk,
        const float* __restrict__ fc, const float* __restrict__ fs,
        const float* __restrict__ sqk){
  int h = blockIdx.x, s = blockIdx.y, b = blockIdx.z, d = threadIdx.x;
  size_t ib = ((size_t)(b*SEQ + s))*DIMN + h*HDIM + d;
  float q = xq[ib], k = xk[ib];
  float qn = __shfl_xor(q, 1), kn = __shfl_xor(k, 1);
  int p = d >> 1;
  float c = fc[s*32 + p], sn = fs[s*32 + p];
  float qr, kr;
  if((d & 1) == 0){ qr = q*c - qn*sn; kr = k*c - kn*sn; }
  else            { qr = qn*sn + q*c; kr = kn*sn + k*c; }
  float sq = qr*qr, sk = kr*kr;
  for(int off = 32; off; off >>= 1){ sq += __shfl_xor(sq, off); sk += __shfl_xor(sk, off); }
  float scl = sqk[h*HDIM + d] * 32.f;
  xq[ib] = scl * qr / fmaxf(sqrtf(sq), 1e-12f);
  xk[ib] = scl * kr / fmaxf(sqrtf(sk), 1e-12f);
}

// ---------------- flash attention over (B,S,DIM)-layout q/k/v ----------------
// grid (SEQ/16, NH, B), block 256. Running m/l kept in registers.
__global__ __launch_bounds__(256) void k_flash(const float* __restrict__ qp,
        const float* __restrict__ kp, const float* __restrict__ vp, float* __restrict__ out){
  int qb = blockIdx.x, h = blockIdx.y, b = blockIdx.z, tid = threadIdx.x;
  __shared__ float Q[16][68], Kc[64][68], Vc[64][68], Sc[16][68], accs[16][68];
  __shared__ float frow[16], lrow[16];
  size_t rowbase = (size_t)b*SEQ*DIMN + h*HDIM;
  int qi0 = tid >> 4, d4 = (tid & 15)*4;
  {
    *(float4*)&Q[qi0][d4] = *(const float4*)(qp + rowbase + (size_t)(qb*16 + qi0)*DIMN + d4);
    for(int r2 = 0; r2 < 4; r2++){ int slot = tid + r2*256; accs[slot >> 6][slot & 63] = 0.f; }
  }
  __syncthreads();
  int qi = tid >> 4, kl = tid & 15;
  float m_run = -INFINITY, l_run = 0.f;
  for(int ch = 0; ch < SEQ/64; ch++){
    for(int r2 = 0; r2 < 4; r2++){
      int row = qi0 + r2*16;
      *(float4*)&Kc[row][d4] = *(const float4*)(kp + rowbase + (size_t)(ch*64 + row)*DIMN + d4);
      *(float4*)&Vc[row][d4] = *(const float4*)(vp + rowbase + (size_t)(ch*64 + row)*DIMN + d4);
    }
    __syncthreads();
    float sreg[4];
    float mloc = -INFINITY;
    #pragma unroll
    for(int it = 0; it < 4; it++){
      int kj = kl + it*16;
      float s = 0.f;
      #pragma unroll
      for(int dd = 0; dd < 64; dd += 4){
        float4 a = *(const float4*)&Q[qi][dd];
        float4 bb = *(const float4*)&Kc[kj][dd];
        s += a.x*bb.x + a.y*bb.y + a.z*bb.z + a.w*bb.w;
      }
      s *= 8.f;
      sreg[it] = s;
      mloc = fmaxf(mloc, s);
    }
    for(int off = 1; off < 16; off <<= 1) mloc = fmaxf(mloc, __shfl_xor(mloc, off));
    float mnew = fmaxf(m_run, mloc);
    float psum = 0.f;
    #pragma unroll
    for(int it = 0; it < 4; it++){
      float e = expf(sreg[it] - mnew);
      Sc[qi][kl + it*16] = e;
      psum += e;
    }
    for(int off = 1; off < 16; off <<= 1) psum += __shfl_xor(psum, off);
    float f = expf(m_run - mnew);          // register only; exp(-inf)=0 on first chunk
    l_run = l_run * f + psum;
    m_run = mnew;
    if(kl == 0){ frow[qi] = f; lrow[qi] = l_run; }
    __syncthreads();
    for(int r2 = 0; r2 < 4; r2++){
      int qi2 = (tid >> 6) + r2*4, d = tid & 63;
      float a = accs[qi2][d] * frow[qi2];
      for(int j2 = 0; j2 < 64; j2++) a += Sc[qi2][j2] * Vc[j2][d];
      accs[qi2][d] = a;
    }
    __syncthreads();
  }
  for(int r2 = 0; r2 < 4; r2++){
    int qi2 = (tid >> 6) + r2*4, d = tid & 63;
    out[rowbase + (size_t)(qb*16 + qi2)*DIMN + d] = accs[qi2][d] / lrow[qi2];
  }
}

// ---------------- block reduce helper ----------------
__device__ __forceinline__ float blockReduceSum(float v, float* red){
  for(int off = 32; off; off >>= 1) v += __shfl_xor(v, off);
  int wid = threadIdx.x >> 6;
  if((threadIdx.x & 63) == 0) red[wid] = v;
  __syncthreads();
  float tot = red[0] + red[1] + red[2] + red[3];
  __syncthreads();
  return tot;
}

// ---------------- xo = justnorm(h + lr*(justnorm(ha) - h)), h = justnorm(x) ----------------
__global__ void k_rn(const float* __restrict__ x, const float* __restrict__ ha,
        const float* __restrict__ alpha, float* __restrict__ xo){
  __shared__ float red[4];
  int row = blockIdx.x, tid = threadIdx.x;
  size_t base = (size_t)row * DIMN;
  float xs[4], hs[4], cs[4];
  float s1 = 0.f, s2 = 0.f;
  for(int j = 0; j < 4; j++){
    int i = tid + j*256;
    float xv = x[base + i];  xs[j] = xv; s1 += xv*xv;
    float hv = ha[base + i]; hs[j] = hv; s2 += hv*hv;
  }
  s1 = blockReduceSum(s1, red);
  s2 = blockReduceSum(s2, red);
  float r1 = 1.f / fmaxf(sqrtf(s1), 1e-12f);
  float r2 = 1.f / fmaxf(sqrtf(s2), 1e-12f);
  float s3 = 0.f;
  for(int j = 0; j < 4; j++){
    int i = tid + j*256;
    float lr = fabsf(alpha[i] * 1.6f);
    float hn = xs[j] * r1;
    float cv = hn + lr*(hs[j]*r2 - hn);
    cs[j] = cv; s3 += cv*cv;
  }
  s3 = blockReduceSum(s3, red);
  float r3 = 1.f / fmaxf(sqrtf(s3), 1e-12f);
  for(int j = 0; j < 4; j++){
    int i = tid + j*256;
    xo[base + i] = cs[j] * r3;
  }
}

// ---------------- FFN elementwise, in place on a1 ----------------
__global__ void k_ffnew(float* __restrict__ a1, const float* __restrict__ a3,
        const float* __restrict__ su, const float* __restrict__ sv){
  int idx = blockIdx.x*256 + threadIdx.x;
  int j = idx % HIDDEN;
  float hpre = a1[idx] * (sv[j] * 53.06599665f);
  float sil = hpre / (1.f + expf(-hpre));
  a1[idx] = sil * (a3[idx] * su[j]);
}

extern "C" void kernel_launch(void* const* d_in, const int* in_sizes, int n_in,
                              void* d_out, int out_size, void* d_ws, size_t ws_size,
                              hipStream_t stream){
  const float* x   = (const float*)d_in[0];
  const float* fc  = (const float*)d_in[1];
  const float* fs  = (const float*)d_in[2];
  const float* ada = (const float*)d_in[3];
  const float* wq  = (const float*)d_in[4];
  const float* wk  = (const float*)d_in[5];
  const float* wv  = (const float*)d_in[6];
  const float* wo  = (const float*)d_in[7];
  const float* sqk = (const float*)d_in[8];
  const float* w1  = (const float*)d_in[9];
  const float* w2  = (const float*)d_in[10];
  const float* w3  = (const float*)d_in[11];
  const float* su  = (const float*)d_in[12];
  const float* sv  = (const float*)d_in[13];
  const float* pw  = (const float*)d_in[14];
  const float* pb  = (const float*)d_in[15];
  const float* aal = (const float*)d_in[16];
  const float* mal = (const float*)d_in[17];
  float* out = (float*)d_out;

  const size_t F = (size_t)ROWS * DIMN;          // 4M elements
  float* ws_f = (float*)d_ws;
  float* t = ws_f;                                // 1024
  float* g = ws_f + 1024;                         // 1024
  float* A  = ws_f + 4096;                        // xmod -> attn_out -> xmod2
  float* Bq = A  + F;                             // xq -> h_a_pre -> h_m
  float* Ck = Bq + F;                             // xk -> x1
  float* Dv = out;                                // xv (d_out as scratch)
  float* a1 = Ck + F;                             // FCHUNK x HIDDEN fp32
  float* a3 = a1 + (size_t)FCHUNK*HIDDEN;
  // ws total ~62 MB

  dim3 blk(256);

  k_time<<<dim3(1024), dim3(64), 0, stream>>>(ada, pw, pb, t);
  k_g<<<dim3(4), blk, 0, stream>>>(t, g);
  k_modulate<<<dim3(64,128,BATCH), blk, 0, stream>>>(x, g, A);

  k_gemm<<<dim3(16,64), blk, 0, stream>>>(A, wq, Bq, ROWS, DIMN, DIMN);
  k_gemm<<<dim3(16,64), blk, 0, stream>>>(A, wk, Ck, ROWS, DIMN, DIMN);
  k_gemm<<<dim3(16,64), blk, 0, stream>>>(A, wv, Dv, ROWS, DIMN, DIMN);

  k_qkvprep<<<dim3(NHEAD,SEQ,BATCH), dim3(64), 0, stream>>>(Bq, Ck, fc, fs, sqk);
  k_flash<<<dim3(SEQ/16,NHEAD,BATCH), blk, 0, stream>>>(Bq, Ck, Dv, A);
  k_gemm<<<dim3(16,64), blk, 0, stream>>>(A, wo, Bq, ROWS, DIMN, DIMN);
  k_rn<<<dim3(ROWS), blk, 0, stream>>>(x, Bq, aal, Ck);

  k_modulate<<<dim3(64,128,BATCH), blk, 0, stream>>>(Ck, g + 512, A);

  for(int c2 = 0; c2 < ROWS/FCHUNK; c2++){
    const float* Ac = A + (size_t)c2*FCHUNK*DIMN;
    float* hmc = Bq + (size_t)c2*FCHUNK*DIMN;
    k_gemm<<<dim3(HIDDEN/64,FCHUNK/64), blk, 0, stream>>>(Ac, w1, a1, FCHUNK, HIDDEN, DIMN);
    k_gemm<<<dim3(HIDDEN/64,FCHUNK/64), blk, 0, stream>>>(Ac, w3, a3, FCHUNK, HIDDEN, DIMN);
    k_ffnew<<<dim3(FCHUNK*HIDDEN/256), blk, 0, stream>>>(a1, a3, su, sv);
    k_gemm<<<dim3(16,FCHUNK/64), blk, 0, stream>>>(a1, w2, hmc, FCHUNK, DIMN, HIDDEN);
  }

  k_rn<<<dim3(ROWS), blk, 0, stream>>>(Ck, Bq, mal, out);
}

// Round 4
// 1223.603 us; speedup vs baseline: 4.2146x; 4.2146x over previous
//
#include <hip/hip_runtime.h>
#include <hip/hip_bf16.h>
#include <math.h>

#define SEQ    2048
#define DIMN   1024
#define NHEAD  16
#define HDIM   64
#define BATCH  2
#define ROWS   (BATCH*SEQ)      // 4096
#define HIDDEN 2816
#define FCHUNK 512

typedef __attribute__((ext_vector_type(8))) short short8;
typedef __attribute__((ext_vector_type(4))) float f32x4;
typedef unsigned short ushort_t;

__device__ __forceinline__ float bfbits(ushort_t u){ return __uint_as_float(((unsigned)u) << 16); }
__device__ __forceinline__ ushort_t f2bu(float f){
  __hip_bfloat16 h = __float2bfloat16(f);
  return *reinterpret_cast<ushort_t*>(&h);
}
__device__ __forceinline__ float ldv(const float* p){ return *p; }
__device__ __forceinline__ float ldv(const ushort_t* p){ return bfbits(*p); }
__device__ __forceinline__ void stv(float* p, float v){ *p = v; }
__device__ __forceinline__ void stv(ushort_t* p, float v){ *p = f2bu(v); }

// ---------------- t = silu(adafm_input) @ proj_w + proj_b (fp32) ----------------
__global__ void k_time(const float* __restrict__ ada, const float* __restrict__ pw,
                       const float* __restrict__ pb, float* __restrict__ t){
  int b = blockIdx.x >> 9, o = blockIdx.x & 511, lane = threadIdx.x;
  float acc = 0.f;
  for(int i = lane; i < DIMN; i += 64){
    float a = ada[b*DIMN + i];
    float s = a / (1.f + expf(-a));
    acc += s * pw[i*512 + o];
  }
  for(int off = 32; off; off >>= 1) acc += __shfl_down(acc, off);
  if(lane == 0) t[b*512 + o] = acc + pb[o];
}

// ---------------- g[which][b][n] = (1/256) sum_k F[k] cos(2*pi*k*n/256) ----------------
__global__ void k_g(const float* __restrict__ t, float* __restrict__ g){
  int which = blockIdx.x >> 1, b = blockIdx.x & 1, n = threadIdx.x;
  const float C = 6.283185307179586f / 256.f;
  float acc = 0.f;
  for(int k = 0; k < 256; k++){
    float f = t[b*512 + which*256 + k];
    acc += f * cosf(C * (float)((k*n) & 255));
  }
  g[which*512 + b*256 + n] = acc * (1.f/256.f);
}

// ---------------- weight transpose: fp32 W[K][N] -> bf16 Wt[N][K] ----------------
__global__ void k_wt(const float* __restrict__ W, ushort_t* __restrict__ Wt, int K, int N){
  __shared__ float tile[32][33];
  int k0 = blockIdx.y*32, n0 = blockIdx.x*32;
  int r = threadIdx.x >> 3, c4 = (threadIdx.x & 7)*4;
  float4 v = *(const float4*)(W + (size_t)(k0 + r)*N + n0 + c4);
  tile[r][c4+0] = v.x; tile[r][c4+1] = v.y; tile[r][c4+2] = v.z; tile[r][c4+3] = v.w;
  __syncthreads();
  ushort4 o;
  o.x = f2bu(tile[c4+0][r]); o.y = f2bu(tile[c4+1][r]);
  o.z = f2bu(tile[c4+2][r]); o.w = f2bu(tile[c4+3][r]);
  *(ushort4*)(Wt + (size_t)(n0 + r)*K + k0 + c4) = o;
}

// ---------------- per-patch circular convolution -> bf16 ----------------
template<typename IN>
__global__ void k_modulate(const IN* __restrict__ src, const float* __restrict__ g,
                           ushort_t* __restrict__ dst){
  __shared__ float v[256];
  __shared__ float gd[512];
  int j = blockIdx.x, i = blockIdx.y, b = blockIdx.z, n = threadIdx.x;
  int r = n >> 4, c = n & 15;
  size_t off = (size_t)b*SEQ*DIMN + (size_t)(i*16 + r)*DIMN + j*16 + c;
  v[n] = ldv(src + off);
  float gv = g[b*256 + n];
  gd[n] = gv; gd[n + 256] = gv;
  __syncthreads();
  float acc = 0.f;
  #pragma unroll 8
  for(int m = 0; m < 256; m++) acc += v[m] * gd[n + 256 - m];
  dst[off] = f2bu(acc);
}

// ---------------- MFMA GEMM: C(MxN) = A(MxK,bf16) @ Wt(NxK,bf16)^T ----------------
// 64x64 tile, 4 waves, K-step 32. mfma_f32_16x16x32_bf16.
#define GSTR 40
template<typename OUT>
__global__ __launch_bounds__(256) void k_gemm_mf(const ushort_t* __restrict__ A,
        const ushort_t* __restrict__ Wt, OUT* __restrict__ C, int M, int N, int K){
  __shared__ __align__(16) ushort_t As[64*GSTR];
  __shared__ __align__(16) ushort_t Ws[64*GSTR];
  int tid = threadIdx.x, lane = tid & 63, w = tid >> 6;
  int l15 = lane & 15, quad = lane >> 4;
  int m0 = blockIdx.y*64, n0 = blockIdx.x*64;
  int r = tid >> 2, c = tid & 3;
  const ushort_t* arow = A  + (size_t)(m0 + r)*K + c*8;
  const ushort_t* wrow = Wt + (size_t)(n0 + r)*K + c*8;
  f32x4 acc[4];
  #pragma unroll
  for(int g2 = 0; g2 < 4; g2++) for(int t2 = 0; t2 < 4; t2++) acc[g2][t2] = 0.f;
  for(int kk = 0; kk < K; kk += 32){
    short8 av = *(const short8*)(arow + kk);
    short8 wv = *(const short8*)(wrow + kk);
    __syncthreads();
    *(short8*)&As[r*GSTR + c*8] = av;
    *(short8*)&Ws[r*GSTR + c*8] = wv;
    __syncthreads();
    short8 af = *(const short8*)&As[(w*16 + l15)*GSTR + quad*8];
    #pragma unroll
    for(int g2 = 0; g2 < 4; g2++){
      short8 bf = *(const short8*)&Ws[(g2*16 + l15)*GSTR + quad*8];
      acc[g2] = __builtin_amdgcn_mfma_f32_16x16x32_bf16(af, bf, acc[g2], 0, 0, 0);
    }
  }
  #pragma unroll
  for(int g2 = 0; g2 < 4; g2++)
    #pragma unroll
    for(int t2 = 0; t2 < 4; t2++)
      stv(C + (size_t)(m0 + w*16 + quad*4 + t2)*N + n0 + g2*16 + l15, acc[g2][t2]);
}

// ---------------- rotary + justnorm + sqk scale, in place, bf16 ----------------
__global__ void k_qkvprep(ushort_t* __restrict__ xq, ushort_t* __restrict__ xk,
        const float* __restrict__ fc, const float* __restrict__ fs,
        const float* __restrict__ sqk){
  int h = blockIdx.x, s = blockIdx.y, b = blockIdx.z, d = threadIdx.x;
  size_t ib = ((size_t)(b*SEQ + s))*DIMN + h*HDIM + d;
  float q = bfbits(xq[ib]), k = bfbits(xk[ib]);
  float qn = __shfl_xor(q, 1), kn = __shfl_xor(k, 1);
  int p = d >> 1;
  float c = fc[s*32 + p], sn = fs[s*32 + p];
  float qr, kr;
  if((d & 1) == 0){ qr = q*c - qn*sn; kr = k*c - kn*sn; }
  else            { qr = qn*sn + q*c; kr = kn*sn + k*c; }
  float sq = qr*qr, sk = kr*kr;
  for(int off = 32; off; off >>= 1){ sq += __shfl_xor(sq, off); sk += __shfl_xor(sk, off); }
  float scl = sqk[h*HDIM + d] * 32.f;
  xq[ib] = f2bu(scl * qr / fmaxf(sqrtf(sq), 1e-12f));
  xk[ib] = f2bu(scl * kr / fmaxf(sqrtf(sk), 1e-12f));
}

// ---------------- MFMA flash attention ----------------
// grid (SEQ/64, NH, B), block 256 (4 waves). Q-tile 64 rows (16/wave), K/V chunk 64.
#define LSTR 72
__global__ __launch_bounds__(256) void k_flash_mf(const ushort_t* __restrict__ qp,
        const ushort_t* __restrict__ kp, const ushort_t* __restrict__ vp,
        ushort_t* __restrict__ out){
  int qb = blockIdx.x, h = blockIdx.y, b = blockIdx.z;
  int tid = threadIdx.x, lane = tid & 63, w = tid >> 6;
  int l15 = lane & 15, quad = lane >> 4;
  __shared__ __align__(16) ushort_t Ks[64*LSTR];
  __shared__ __align__(16) ushort_t Vts[64*LSTR];
  __shared__ __align__(16) ushort_t Ps[4][16*LSTR];
  size_t hb = (size_t)b*SEQ*DIMN + h*HDIM;

  short8 qf0, qf1;
  {
    const ushort_t* qrow = qp + hb + (size_t)(qb*64 + w*16 + l15)*DIMN;
    qf0 = *(const short8*)(qrow + quad*8);
    qf1 = *(const short8*)(qrow + 32 + quad*8);
  }
  f32x4 o_acc[4];
  float m_run[4], l_run[4];
  #pragma unroll
  for(int t = 0; t < 4; t++){
    m_run[t] = -INFINITY; l_run[t] = 0.f;
    o_acc[t][0] = 0.f; o_acc[t][1] = 0.f; o_acc[t][2] = 0.f; o_acc[t][3] = 0.f;
  }
  int sr = tid >> 2, sc = tid & 3;
  for(int ch = 0; ch < SEQ/64; ch++){
    __syncthreads();   // previous iteration's PV reads of Vts/Ks complete
    {
      const ushort_t* krow = kp + hb + (size_t)(ch*64 + sr)*DIMN;
      *(short8*)&Ks[sr*LSTR + sc*16]     = *(const short8*)(krow + sc*16);
      *(short8*)&Ks[sr*LSTR + sc*16 + 8] = *(const short8*)(krow + sc*16 + 8);
      const ushort_t* vrow = vp + hb + (size_t)(ch*64 + sr)*DIMN;
      short8 v0 = *(const short8*)(vrow + sc*16);
      short8 v1 = *(const short8*)(vrow + sc*16 + 8);
      #pragma unroll
      for(int jj = 0; jj < 8; jj++){
        Vts[(sc*16 + jj)*LSTR + sr]     = (ushort_t)v0[jj];
        Vts[(sc*16 + 8 + jj)*LSTR + sr] = (ushort_t)v1[jj];
      }
    }
    __syncthreads();
    // S = Q K^T  (16 q rows per wave x 64 kj)
    f32x4 s_acc[4];
    #pragma unroll
    for(int g = 0; g < 4; g++){
      f32x4 sa; sa[0]=0.f; sa[1]=0.f; sa[2]=0.f; sa[3]=0.f;
      short8 b0 = *(const short8*)&Ks[(g*16 + l15)*LSTR + quad*8];
      short8 b1 = *(const short8*)&Ks[(g*16 + l15)*LSTR + 32 + quad*8];
      sa = __builtin_amdgcn_mfma_f32_16x16x32_bf16(qf0, b0, sa, 0, 0, 0);
      sa = __builtin_amdgcn_mfma_f32_16x16x32_bf16(qf1, b1, sa, 0, 0, 0);
      s_acc[g] = sa;
    }
    // online softmax per C-row (row = quad*4 + t, col = l15 within 16-lane group)
    float f_[4];
    #pragma unroll
    for(int t = 0; t < 4; t++){
      float s0 = s_acc[0][t]*8.f, s1 = s_acc[1][t]*8.f, s2 = s_acc[2][t]*8.f, s3 = s_acc[3][t]*8.f;
      float m = fmaxf(fmaxf(s0, s1), fmaxf(s2, s3));
      for(int off = 1; off < 16; off <<= 1) m = fmaxf(m, __shfl_xor(m, off));
      float mnew = fmaxf(m_run[t], m);
      float e0 = expf(s0 - mnew), e1 = expf(s1 - mnew), e2 = expf(s2 - mnew), e3 = expf(s3 - mnew);
      int prow = (quad*4 + t)*LSTR + l15;
      Ps[w][prow]      = f2bu(e0);
      Ps[w][prow + 16] = f2bu(e1);
      Ps[w][prow + 32] = f2bu(e2);
      Ps[w][prow + 48] = f2bu(e3);
      float ps = e0 + e1 + e2 + e3;
      for(int off = 1; off < 16; off <<= 1) ps += __shfl_xor(ps, off);
      f_[t] = expf(m_run[t] - mnew);
      l_run[t] = l_run[t]*f_[t] + ps;
      m_run[t] = mnew;
    }
    __syncthreads();   // Ps visible (also keeps waves in phase)
    // O += P V   (A = Ps [q][kj], B = Vts [d][kj])
    short8 a0 = *(const short8*)&Ps[w][l15*LSTR + quad*8];
    short8 a1 = *(const short8*)&Ps[w][l15*LSTR + 32 + quad*8];
    #pragma unroll
    for(int g = 0; g < 4; g++){
      f32x4 oa = o_acc[g];
      oa[0] *= f_[0]; oa[1] *= f_[1]; oa[2] *= f_[2]; oa[3] *= f_[3];
      short8 b0 = *(const short8*)&Vts[(g*16 + l15)*LSTR + quad*8];
      short8 b1 = *(const short8*)&Vts[(g*16 + l15)*LSTR + 32 + quad*8];
      oa = __builtin_amdgcn_mfma_f32_16x16x32_bf16(a0, b0, oa, 0, 0, 0);
      oa = __builtin_amdgcn_mfma_f32_16x16x32_bf16(a1, b1, oa, 0, 0, 0);
      o_acc[g] = oa;
    }
  }
  #pragma unroll
  for(int g = 0; g < 4; g++)
    #pragma unroll
    for(int t = 0; t < 4; t++)
      out[hb + (size_t)(qb*64 + w*16 + quad*4 + t)*DIMN + g*16 + l15] = f2bu(o_acc[g][t] / l_run[t]);
}

// ---------------- block reduce helper ----------------
__device__ __forceinline__ float blockReduceSum(float v, float* red){
  for(int off = 32; off; off >>= 1) v += __shfl_xor(v, off);
  int wid = threadIdx.x >> 6;
  if((threadIdx.x & 63) == 0) red[wid] = v;
  __syncthreads();
  float tot = red[0] + red[1] + red[2] + red[3];
  __syncthreads();
  return tot;
}

// ---------------- xo = justnorm(h + lr*(justnorm(ha) - h)), h = justnorm(x) ----------------
template<typename T1, typename T2, typename TO>
__global__ void k_rn(const T1* __restrict__ x, const T2* __restrict__ ha,
        const float* __restrict__ alpha, TO* __restrict__ xo){
  __shared__ float red[4];
  int row = blockIdx.x, tid = threadIdx.x;
  size_t base = (size_t)row * DIMN;
  float xs[4], hs[4], cs[4];
  float s1 = 0.f, s2 = 0.f;
  for(int j = 0; j < 4; j++){
    int i = tid + j*256;
    float xv = ldv(x + base + i);  xs[j] = xv; s1 += xv*xv;
    float hv = ldv(ha + base + i); hs[j] = hv; s2 += hv*hv;
  }
  s1 = blockReduceSum(s1, red);
  s2 = blockReduceSum(s2, red);
  float r1 = 1.f / fmaxf(sqrtf(s1), 1e-12f);
  float r2 = 1.f / fmaxf(sqrtf(s2), 1e-12f);
  float s3 = 0.f;
  for(int j = 0; j < 4; j++){
    int i = tid + j*256;
    float lr = fabsf(alpha[i] * 1.6f);
    float hn = xs[j] * r1;
    float cv = hn + lr*(hs[j]*r2 - hn);
    cs[j] = cv; s3 += cv*cv;
  }
  s3 = blockReduceSum(s3, red);
  float r3 = 1.f / fmaxf(sqrtf(s3), 1e-12f);
  for(int j = 0; j < 4; j++){
    int i = tid + j*256;
    stv(xo + base + i, cs[j] * r3);
  }
}

// ---------------- FFN elementwise, in place on a1 (bf16) ----------------
__global__ void k_ffnew(ushort_t* __restrict__ a1, const ushort_t* __restrict__ a3,
        const float* __restrict__ su, const float* __restrict__ sv){
  int idx = blockIdx.x*256 + threadIdx.x;
  int j = idx % HIDDEN;
  float hpre = bfbits(a1[idx]) * (sv[j] * 53.06599665f);
  float sil = hpre / (1.f + expf(-hpre));
  a1[idx] = f2bu(sil * (bfbits(a3[idx]) * su[j]));
}

extern "C" void kernel_launch(void* const* d_in, const int* in_sizes, int n_in,
                              void* d_out, int out_size, void* d_ws, size_t ws_size,
                              hipStream_t stream){
  const float* x   = (const float*)d_in[0];
  const float* fc  = (const float*)d_in[1];
  const float* fs  = (const float*)d_in[2];
  const float* ada = (const float*)d_in[3];
  const float* wq  = (const float*)d_in[4];
  const float* wk  = (const float*)d_in[5];
  const float* wv  = (const float*)d_in[6];
  const float* wo  = (const float*)d_in[7];
  const float* sqk = (const float*)d_in[8];
  const float* w1  = (const float*)d_in[9];
  const float* w2  = (const float*)d_in[10];
  const float* w3  = (const float*)d_in[11];
  const float* su  = (const float*)d_in[12];
  const float* sv  = (const float*)d_in[13];
  const float* pw  = (const float*)d_in[14];
  const float* pb  = (const float*)d_in[15];
  const float* aal = (const float*)d_in[16];
  const float* mal = (const float*)d_in[17];
  float* out = (float*)d_out;

  const size_t F = (size_t)ROWS * DIMN;           // 4M elements
  float* t = (float*)d_ws;                        // 1024
  float* g = t + 1024;                            // 1024
  ushort_t* wqT = (ushort_t*)(g + 1024 + 2048);   // [1024][1024] bf16
  ushort_t* wkT = wqT + (size_t)DIMN*DIMN;
  ushort_t* wvT = wkT + (size_t)DIMN*DIMN;
  ushort_t* woT = wvT + (size_t)DIMN*DIMN;
  ushort_t* w1T = woT + (size_t)DIMN*DIMN;        // [2816][1024]
  ushort_t* w3T = w1T + (size_t)HIDDEN*DIMN;
  ushort_t* w2T = w3T + (size_t)HIDDEN*DIMN;      // [1024][2816]
  ushort_t* P1  = w2T + (size_t)DIMN*HIDDEN;      // xmod -> attn_out -> xmod2
  ushort_t* P2  = P1 + F;                         // q -> x1
  ushort_t* P3  = P2 + F;                         // k -> h_a -> h_m
  ushort_t* a1  = P3 + F;                         // [FCHUNK][HIDDEN]
  ushort_t* a3  = a1 + (size_t)FCHUNK*HIDDEN;
  ushort_t* Dv  = (ushort_t*)d_out;               // v lives in d_out until final write

  dim3 blk(256);

  // time projection + conv kernels
  k_time<<<dim3(1024), dim3(64), 0, stream>>>(ada, pw, pb, t);
  k_g<<<dim3(4), blk, 0, stream>>>(t, g);

  // weight transposes fp32 -> bf16 [N][K]
  k_wt<<<dim3(32,32), blk, 0, stream>>>(wq, wqT, DIMN, DIMN);
  k_wt<<<dim3(32,32), blk, 0, stream>>>(wk, wkT, DIMN, DIMN);
  k_wt<<<dim3(32,32), blk, 0, stream>>>(wv, wvT, DIMN, DIMN);
  k_wt<<<dim3(32,32), blk, 0, stream>>>(wo, woT, DIMN, DIMN);
  k_wt<<<dim3(HIDDEN/32,32), blk, 0, stream>>>(w1, w1T, DIMN, HIDDEN);
  k_wt<<<dim3(HIDDEN/32,32), blk, 0, stream>>>(w3, w3T, DIMN, HIDDEN);
  k_wt<<<dim3(32,HIDDEN/32), blk, 0, stream>>>(w2, w2T, HIDDEN, DIMN);

  // attention branch
  k_modulate<float><<<dim3(64,128,BATCH), blk, 0, stream>>>(x, g, P1);
  k_gemm_mf<ushort_t><<<dim3(16,64), blk, 0, stream>>>(P1, wqT, P2, ROWS, DIMN, DIMN);
  k_gemm_mf<ushort_t><<<dim3(16,64), blk, 0, stream>>>(P1, wkT, P3, ROWS, DIMN, DIMN);
  k_gemm_mf<ushort_t><<<dim3(16,64), blk, 0, stream>>>(P1, wvT, Dv, ROWS, DIMN, DIMN);
  k_qkvprep<<<dim3(NHEAD,SEQ,BATCH), dim3(64), 0, stream>>>(P2, P3, fc, fs, sqk);
  k_flash_mf<<<dim3(SEQ/64,NHEAD,BATCH), blk, 0, stream>>>(P2, P3, Dv, P1);
  k_gemm_mf<ushort_t><<<dim3(16,64), blk, 0, stream>>>(P1, woT, P3, ROWS, DIMN, DIMN);
  k_rn<float,ushort_t,ushort_t><<<dim3(ROWS), blk, 0, stream>>>(x, P3, aal, P2);

  // FFN branch
  k_modulate<ushort_t><<<dim3(64,128,BATCH), blk, 0, stream>>>(P2, g + 512, P1);
  for(int c2 = 0; c2 < ROWS/FCHUNK; c2++){
    const ushort_t* Ac = P1 + (size_t)c2*FCHUNK*DIMN;
    ushort_t* hmc = P3 + (size_t)c2*FCHUNK*DIMN;
    k_gemm_mf<ushort_t><<<dim3(HIDDEN/64,FCHUNK/64), blk, 0, stream>>>(Ac, w1T, a1, FCHUNK, HIDDEN, DIMN);
    k_gemm_mf<ushort_t><<<dim3(HIDDEN/64,FCHUNK/64), blk, 0, stream>>>(Ac, w3T, a3, FCHUNK, HIDDEN, DIMN);
    k_ffnew<<<dim3(FCHUNK*HIDDEN/256), blk, 0, stream>>>(a1, a3, su, sv);
    k_gemm_mf<ushort_t><<<dim3(16,FCHUNK/64), blk, 0, stream>>>(a1, w2T, hmc, FCHUNK, DIMN, HIDDEN);
  }

  k_rn<ushort_t,ushort_t,float><<<dim3(ROWS), blk, 0, stream>>>(P2, P3, mal, out);
}

// Round 5
// 885.962 us; speedup vs baseline: 5.8208x; 1.3811x over previous
//
#include <hip/hip_runtime.h>
#include <hip/hip_bf16.h>
#include <math.h>

#define SEQ    2048
#define DIMN   1024
#define NHEAD  16
#define HDIM   64
#define BATCH  2
#define ROWS   4096
#define HIDDEN 2816
#define FCHUNK 1024

typedef __attribute__((ext_vector_type(8))) short short8;
typedef __attribute__((ext_vector_type(4))) float f32x4;
typedef unsigned short ushort_t;
typedef __attribute__((address_space(1))) void gas_t;
typedef __attribute__((address_space(3))) void las_t;

__device__ __forceinline__ float bfbits(ushort_t u){ return __uint_as_float(((unsigned)u) << 16); }
__device__ __forceinline__ ushort_t f2bu(float f){
  __hip_bfloat16 h = __float2bfloat16(f);
  return *reinterpret_cast<ushort_t*>(&h);
}
__device__ __forceinline__ float ldv(const float* p){ return *p; }
__device__ __forceinline__ float ldv(const ushort_t* p){ return bfbits(*p); }
__device__ __forceinline__ void stv(float* p, float v){ *p = v; }
__device__ __forceinline__ void stv(ushort_t* p, float v){ *p = f2bu(v); }
__device__ __forceinline__ void async_cp16(const ushort_t* g, ushort_t* l){
  __builtin_amdgcn_global_load_lds((gas_t*)g, (las_t*)l, 16, 0, 0);
}

// ---------------- t = silu(adafm_input) @ proj_w + proj_b ----------------
__global__ void k_time(const float* __restrict__ ada, const float* __restrict__ pw,
                       const float* __restrict__ pb, float* __restrict__ t){
  int b = blockIdx.x >> 9, o = blockIdx.x & 511, lane = threadIdx.x;
  float acc = 0.f;
  for(int i = lane; i < DIMN; i += 64){
    float a = ada[b*DIMN + i];
    float s = a / (1.f + expf(-a));
    acc += s * pw[i*512 + o];
  }
  for(int off = 32; off; off >>= 1) acc += __shfl_down(acc, off);
  if(lane == 0) t[b*512 + o] = acc + pb[o];
}

// ---------------- g[which][b][n] = (1/256) sum_k F[k] cos(2*pi*k*n/256) ----------------
__global__ void k_g(const float* __restrict__ t, float* __restrict__ g){
  int which = blockIdx.x >> 1, b = blockIdx.x & 1, n = threadIdx.x;
  const float C = 6.283185307179586f / 256.f;
  float acc = 0.f;
  for(int k = 0; k < 256; k++){
    float f = t[b*512 + which*256 + k];
    acc += f * cosf(C * (float)((k*n) & 255));
  }
  g[which*512 + b*256 + n] = acc * (1.f/256.f);
}

// ---------------- weight transpose: fp32 W[K][N] -> bf16 Wt[N][K] ----------------
__global__ void k_wt(const float* __restrict__ W, ushort_t* __restrict__ Wt, int K, int N){
  __shared__ float tile[32][33];
  int k0 = blockIdx.y*32, n0 = blockIdx.x*32;
  int r = threadIdx.x >> 3, c4 = (threadIdx.x & 7)*4;
  float4 v = *(const float4*)(W + (size_t)(k0 + r)*N + n0 + c4);
  tile[r][c4+0] = v.x; tile[r][c4+1] = v.y; tile[r][c4+2] = v.z; tile[r][c4+3] = v.w;
  __syncthreads();
  ushort4 o;
  o.x = f2bu(tile[c4+0][r]); o.y = f2bu(tile[c4+1][r]);
  o.z = f2bu(tile[c4+2][r]); o.w = f2bu(tile[c4+3][r]);
  *(ushort4*)(Wt + (size_t)(n0 + r)*K + k0 + c4) = o;
}

// ---------------- per-patch circular convolution -> bf16 ----------------
template<typename IN>
__global__ void k_modulate(const IN* __restrict__ src, const float* __restrict__ g,
                           ushort_t* __restrict__ dst){
  __shared__ float v[256];
  __shared__ float gd[512];
  int j = blockIdx.x, i = blockIdx.y, b = blockIdx.z, n = threadIdx.x;
  int r = n >> 4, c = n & 15;
  size_t off = (size_t)b*SEQ*DIMN + (size_t)(i*16 + r)*DIMN + j*16 + c;
  v[n] = ldv(src + off);
  float gv = g[b*256 + n];
  gd[n] = gv; gd[n + 256] = gv;
  __syncthreads();
  float acc = 0.f;
  #pragma unroll 8
  for(int m = 0; m < 256; m++) acc += v[m] * gd[n + 256 - m];
  dst[off] = f2bu(acc);
}

// ---------------- m97-style MFMA GEMM: C(MxN) = A(MxK) @ Wt(NxK)^T ----------------
// BMxBN tile, 4 waves (2x2), BK=32, global_load_lds width-16 staging.
template<int BM, int BN, typename OUT>
__global__ __launch_bounds__(256) void k_gemm_mf(const ushort_t* __restrict__ A,
        const ushort_t* __restrict__ Wt, OUT* __restrict__ C, int N, int K){
  constexpr int MT = BM/32, NT = BN/32;
  constexpr int AI = BM/64, BI = BN/64;
  __shared__ __align__(16) ushort_t As[BM*32];
  __shared__ __align__(16) ushort_t Bs[BN*32];
  int tid = threadIdx.x, lane = tid & 63, w = tid >> 6;
  int l15 = lane & 15, quad = lane >> 4;
  int m0 = blockIdx.y*BM, n0 = blockIdx.x*BN;
  int wr = (w>>1)*(BM/2), wc = (w&1)*(BN/2);
  int srow = lane >> 2, scol = (lane & 3)*8;
  const ushort_t* ag[AI]; ushort_t* al[AI];
  const ushort_t* bg[BI]; ushort_t* bl[BI];
  #pragma unroll
  for(int i = 0; i < AI; i++){
    int rb = w*AI + i;
    ag[i] = A + (size_t)(m0 + rb*16 + srow)*K + scol;
    al[i] = As + rb*512 + lane*8;
  }
  #pragma unroll
  for(int i = 0; i < BI; i++){
    int rb = w*BI + i;
    bg[i] = Wt + (size_t)(n0 + rb*16 + srow)*K + scol;
    bl[i] = Bs + rb*512 + lane*8;
  }
  f32x4 acc[MT][NT];
  #pragma unroll
  for(int mt = 0; mt < MT; mt++)
    #pragma unroll
    for(int nt = 0; nt < NT; nt++)
      for(int t = 0; t < 4; t++) acc[mt][nt][t] = 0.f;
  for(int kk = 0; kk < K; kk += 32){
    __syncthreads();
    #pragma unroll
    for(int i = 0; i < AI; i++) async_cp16(ag[i] + kk, al[i]);
    #pragma unroll
    for(int i = 0; i < BI; i++) async_cp16(bg[i] + kk, bl[i]);
    __syncthreads();
    short8 af[MT], bf[NT];
    #pragma unroll
    for(int mt = 0; mt < MT; mt++) af[mt] = *(const short8*)&As[(wr + mt*16 + l15)*32 + quad*8];
    #pragma unroll
    for(int nt = 0; nt < NT; nt++) bf[nt] = *(const short8*)&Bs[(wc + nt*16 + l15)*32 + quad*8];
    #pragma unroll
    for(int mt = 0; mt < MT; mt++)
      #pragma unroll
      for(int nt = 0; nt < NT; nt++)
        acc[mt][nt] = __builtin_amdgcn_mfma_f32_16x16x32_bf16(af[mt], bf[nt], acc[mt][nt], 0, 0, 0);
  }
  #pragma unroll
  for(int mt = 0; mt < MT; mt++)
    #pragma unroll
    for(int nt = 0; nt < NT; nt++)
      #pragma unroll
      for(int t = 0; t < 4; t++)
        stv(C + (size_t)(m0 + wr + mt*16 + quad*4 + t)*N + n0 + wc + nt*16 + l15, acc[mt][nt][t]);
}

// ---------------- rotary + justnorm + sqk scale, in place, 4 heads/block ----------------
__global__ void k_qkvprep(ushort_t* __restrict__ xq, ushort_t* __restrict__ xk,
        const float* __restrict__ fc, const float* __restrict__ fs,
        const float* __restrict__ sqk){
  int w = threadIdx.x >> 6, d = threadIdx.x & 63;
  int h = blockIdx.x*4 + w, s = blockIdx.y, b = blockIdx.z;
  size_t ib = ((size_t)(b*SEQ + s))*DIMN + h*HDIM + d;
  float q = bfbits(xq[ib]), k = bfbits(xk[ib]);
  float qn = __shfl_xor(q, 1), kn = __shfl_xor(k, 1);
  int p = d >> 1;
  float c = fc[s*32 + p], sn = fs[s*32 + p];
  float qr, kr;
  if((d & 1) == 0){ qr = q*c - qn*sn; kr = k*c - kn*sn; }
  else            { qr = qn*sn + q*c; kr = kn*sn + k*c; }
  float sq = qr*qr, sk = kr*kr;
  for(int off = 32; off; off >>= 1){ sq += __shfl_xor(sq, off); sk += __shfl_xor(sk, off); }
  float scl = sqk[h*HDIM + d] * 32.f;
  xq[ib] = f2bu(scl * qr / fmaxf(sqrtf(sq), 1e-12f));
  xk[ib] = f2bu(scl * kr / fmaxf(sqrtf(sk), 1e-12f));
}

// ---------------- V transpose to [b][h][d][s] ----------------
__global__ void k_vt(const ushort_t* __restrict__ v, ushort_t* __restrict__ vto){
  __shared__ ushort_t tile[64][72];
  int s0 = blockIdx.x*64, h = blockIdx.y, b = blockIdx.z;
  int r = threadIdx.x >> 2, c = (threadIdx.x & 3)*16;
  const ushort_t* src = v + (size_t)(b*SEQ + s0 + r)*DIMN + h*HDIM + c;
  *(short8*)&tile[r][c]     = *(const short8*)src;
  *(short8*)&tile[r][c + 8] = *(const short8*)(src + 8);
  __syncthreads();
  ushort_t* dst = vto + ((size_t)(b*NHEAD + h)*HDIM + r)*SEQ + s0 + c;
  for(int j = 0; j < 16; j += 4){
    ushort4 o;
    o.x = tile[c+j][r]; o.y = tile[c+j+1][r]; o.z = tile[c+j+2][r]; o.w = tile[c+j+3][r];
    *(ushort4*)(dst + j) = o;
  }
}

// ---------------- MFMA flash attention, fixed-max softmax ----------------
// grid (SEQ/64, NH, B), 4 waves. S^T = K Q^T so P transform is packed b64 writes.
#define LSTR 72
__global__ __launch_bounds__(256) void k_flash_mf(const ushort_t* __restrict__ qp,
        const ushort_t* __restrict__ kp, const ushort_t* __restrict__ vt,
        ushort_t* __restrict__ out){
  int qb = blockIdx.x, h = blockIdx.y, b = blockIdx.z;
  int tid = threadIdx.x, lane = tid & 63, w = tid >> 6;
  int l15 = lane & 15, quad = lane >> 4;
  __shared__ __align__(16) ushort_t Ks[64*LSTR], Vts[64*LSTR];
  __shared__ __align__(16) ushort_t Ps[4][16*LSTR];
  size_t hb = (size_t)b*SEQ*DIMN + h*HDIM;
  const ushort_t* vb = vt + (size_t)(b*NHEAD + h)*HDIM*SEQ;
  short8 qf0, qf1;
  {
    const ushort_t* qrow = qp + hb + (size_t)(qb*64 + w*16 + l15)*DIMN;
    qf0 = *(const short8*)(qrow + quad*8);
    qf1 = *(const short8*)(qrow + 32 + quad*8);
  }
  f32x4 o_acc[4];
  #pragma unroll
  for(int g = 0; g < 4; g++) for(int t = 0; t < 4; t++) o_acc[g][t] = 0.f;
  float lsum = 0.f;
  int sr = tid >> 2, sc = tid & 3;
  const float C1 = 11.54156036f;   // 8*log2(e)
  const float C2 = 11.90223409f;   // 8.25*log2(e): scores provably < 8.04
  for(int ch = 0; ch < SEQ/64; ch++){
    __syncthreads();
    {
      const ushort_t* krow = kp + hb + (size_t)(ch*64 + sr)*DIMN + sc*16;
      short8 k0 = *(const short8*)krow, k1 = *(const short8*)(krow + 8);
      const ushort_t* vrow = vb + (size_t)sr*SEQ + ch*64 + sc*16;
      short8 v0 = *(const short8*)vrow, v1 = *(const short8*)(vrow + 8);
      *(short8*)&Ks[sr*LSTR + sc*16]      = k0;
      *(short8*)&Ks[sr*LSTR + sc*16 + 8]  = k1;
      *(short8*)&Vts[sr*LSTR + sc*16]     = v0;
      *(short8*)&Vts[sr*LSTR + sc*16 + 8] = v1;
    }
    __syncthreads();
    // S^T = K Q^T : C rows = kj, cols = q
    #pragma unroll
    for(int g = 0; g < 4; g++){
      f32x4 sa; sa[0] = 0.f; sa[1] = 0.f; sa[2] = 0.f; sa[3] = 0.f;
      short8 k0 = *(const short8*)&Ks[(g*16 + l15)*LSTR + quad*8];
      short8 k1 = *(const short8*)&Ks[(g*16 + l15)*LSTR + 32 + quad*8];
      sa = __builtin_amdgcn_mfma_f32_16x16x32_bf16(k0, qf0, sa, 0, 0, 0);
      sa = __builtin_amdgcn_mfma_f32_16x16x32_bf16(k1, qf1, sa, 0, 0, 0);
      float e0 = exp2f(fmaf(sa[0], C1, -C2));
      float e1 = exp2f(fmaf(sa[1], C1, -C2));
      float e2 = exp2f(fmaf(sa[2], C1, -C2));
      float e3 = exp2f(fmaf(sa[3], C1, -C2));
      lsum += (e0 + e1) + (e2 + e3);
      ushort4 pk;
      pk.x = f2bu(e0); pk.y = f2bu(e1); pk.z = f2bu(e2); pk.w = f2bu(e3);
      // P[q=l15][kj = g*16 + quad*4 + 0..3]
      *(ushort4*)&Ps[w][l15*LSTR + g*16 + quad*4] = pk;
    }
    // O += P V  (A = P[q][kj], B = V^T[d][kj])
    short8 a0 = *(const short8*)&Ps[w][l15*LSTR + quad*8];
    short8 a1 = *(const short8*)&Ps[w][l15*LSTR + 32 + quad*8];
    #pragma unroll
    for(int g = 0; g < 4; g++){
      short8 b0 = *(const short8*)&Vts[(g*16 + l15)*LSTR + quad*8];
      short8 b1 = *(const short8*)&Vts[(g*16 + l15)*LSTR + 32 + quad*8];
      o_acc[g] = __builtin_amdgcn_mfma_f32_16x16x32_bf16(a0, b0, o_acc[g], 0, 0, 0);
      o_acc[g] = __builtin_amdgcn_mfma_f32_16x16x32_bf16(a1, b1, o_acc[g], 0, 0, 0);
    }
  }
  // lsum currently holds partials for q=l15 over this lane's kj subset -> reduce over quads
  lsum += __shfl_xor(lsum, 16);
  lsum += __shfl_xor(lsum, 32);
  #pragma unroll
  for(int t = 0; t < 4; t++){
    float lr = __shfl(lsum, quad*4 + t);
    float inv = 1.f / lr;
    #pragma unroll
    for(int g = 0; g < 4; g++)
      out[hb + (size_t)(qb*64 + w*16 + quad*4 + t)*DIMN + g*16 + l15] = f2bu(o_acc[g][t] * inv);
  }
}

// ---------------- block reduce helper ----------------
__device__ __forceinline__ float blockReduceSum(float v, float* red){
  for(int off = 32; off; off >>= 1) v += __shfl_xor(v, off);
  int wid = threadIdx.x >> 6;
  if((threadIdx.x & 63) == 0) red[wid] = v;
  __syncthreads();
  float tot = red[0] + red[1] + red[2] + red[3];
  __syncthreads();
  return tot;
}

// ---------------- xo = justnorm(h + lr*(justnorm(ha) - h)), h = justnorm(x) ----------------
template<typename T1, typename T2, typename TO>
__global__ void k_rn(const T1* __restrict__ x, const T2* __restrict__ ha,
        const float* __restrict__ alpha, TO* __restrict__ xo){
  __shared__ float red[4];
  int row = blockIdx.x, tid = threadIdx.x;
  size_t base = (size_t)row * DIMN;
  float xs[4], hs[4], cs[4];
  float s1 = 0.f, s2 = 0.f;
  for(int j = 0; j < 4; j++){
    int i = tid + j*256;
    float xv = ldv(x + base + i);  xs[j] = xv; s1 += xv*xv;
    float hv = ldv(ha + base + i); hs[j] = hv; s2 += hv*hv;
  }
  s1 = blockReduceSum(s1, red);
  s2 = blockReduceSum(s2, red);
  float r1 = 1.f / fmaxf(sqrtf(s1), 1e-12f);
  float r2 = 1.f / fmaxf(sqrtf(s2), 1e-12f);
  float s3 = 0.f;
  for(int j = 0; j < 4; j++){
    int i = tid + j*256;
    float lr = fabsf(alpha[i] * 1.6f);
    float hn = xs[j] * r1;
    float cv = hn + lr*(hs[j]*r2 - hn);
    cs[j] = cv; s3 += cv*cv;
  }
  s3 = blockReduceSum(s3, red);
  float r3 = 1.f / fmaxf(sqrtf(s3), 1e-12f);
  for(int j = 0; j < 4; j++){
    int i = tid + j*256;
    stv(xo + base + i, cs[j] * r3);
  }
}

// ---------------- FFN elementwise, in place on a1 (bf16) ----------------
__global__ void k_ffnew(ushort_t* __restrict__ a1, const ushort_t* __restrict__ a3,
        const float* __restrict__ su, const float* __restrict__ sv){
  int idx = blockIdx.x*256 + threadIdx.x;
  int j = idx % HIDDEN;
  float hpre = bfbits(a1[idx]) * (sv[j] * 53.06599665f);
  float sil = hpre / (1.f + expf(-hpre));
  a1[idx] = f2bu(sil * (bfbits(a3[idx]) * su[j]));
}

extern "C" void kernel_launch(void* const* d_in, const int* in_sizes, int n_in,
                              void* d_out, int out_size, void* d_ws, size_t ws_size,
                              hipStream_t stream){
  const float* x   = (const float*)d_in[0];
  const float* fc  = (const float*)d_in[1];
  const float* fs  = (const float*)d_in[2];
  const float* ada = (const float*)d_in[3];
  const float* wq  = (const float*)d_in[4];
  const float* wk  = (const float*)d_in[5];
  const float* wv  = (const float*)d_in[6];
  const float* wo  = (const float*)d_in[7];
  const float* sqk = (const float*)d_in[8];
  const float* w1  = (const float*)d_in[9];
  const float* w2  = (const float*)d_in[10];
  const float* w3  = (const float*)d_in[11];
  const float* su  = (const float*)d_in[12];
  const float* sv  = (const float*)d_in[13];
  const float* pw  = (const float*)d_in[14];
  const float* pb  = (const float*)d_in[15];
  const float* aal = (const float*)d_in[16];
  const float* mal = (const float*)d_in[17];
  float* out = (float*)d_out;

  const size_t MM = (size_t)DIMN*DIMN;        // 1M
  const size_t HM = (size_t)HIDDEN*DIMN;      // 2.88M
  const size_t F  = (size_t)ROWS*DIMN;        // 4M
  char* wsb = (char*)d_ws;
  float* t = (float*)wsb;                     // 1024
  float* g = t + 1024;                        // 1024
  ushort_t* wqT = (ushort_t*)(wsb + 16384);
  ushort_t* wkT = wqT + MM;
  ushort_t* wvT = wkT + MM;
  ushort_t* woT = wvT + MM;
  ushort_t* w1T = woT + MM;                   // [2816][1024]
  ushort_t* w3T = w1T + HM;
  ushort_t* w2T = w3T + HM;                   // [1024][2816]
  ushort_t* P1  = w2T + HM;                   // xmod -> attnO -> xmod2
  ushort_t* P2  = P1 + F;                     // q -> x1
  ushort_t* Kb  = P2 + F;                     // k -> h_m
  ushort_t* Vb  = Kb + F;                     // v -> h_a
  ushort_t* a1c = Vb + F;                     // [1024][2816]; also hosts Vt during attention
  ushort_t* a3c = a1c + HM;
  ushort_t* Vt  = a1c;                        // [B][NH][64][SEQ] = 4M el <= 5.77M

  dim3 blk(256);

  k_time<<<dim3(1024), dim3(64), 0, stream>>>(ada, pw, pb, t);
  k_g<<<dim3(4), blk, 0, stream>>>(t, g);

  k_wt<<<dim3(32,32), blk, 0, stream>>>(wq, wqT, DIMN, DIMN);
  k_wt<<<dim3(32,32), blk, 0, stream>>>(wk, wkT, DIMN, DIMN);
  k_wt<<<dim3(32,32), blk, 0, stream>>>(wv, wvT, DIMN, DIMN);
  k_wt<<<dim3(32,32), blk, 0, stream>>>(wo, woT, DIMN, DIMN);
  k_wt<<<dim3(HIDDEN/32,32), blk, 0, stream>>>(w1, w1T, DIMN, HIDDEN);
  k_wt<<<dim3(HIDDEN/32,32), blk, 0, stream>>>(w3, w3T, DIMN, HIDDEN);
  k_wt<<<dim3(32,HIDDEN/32), blk, 0, stream>>>(w2, w2T, HIDDEN, DIMN);

  // attention branch
  k_modulate<float><<<dim3(64,128,BATCH), blk, 0, stream>>>(x, g, P1);
  k_gemm_mf<128,64,ushort_t><<<dim3(16,32), blk, 0, stream>>>(P1, wqT, P2, DIMN, DIMN);
  k_gemm_mf<128,64,ushort_t><<<dim3(16,32), blk, 0, stream>>>(P1, wkT, Kb, DIMN, DIMN);
  k_gemm_mf<128,64,ushort_t><<<dim3(16,32), blk, 0, stream>>>(P1, wvT, Vb, DIMN, DIMN);
  k_qkvprep<<<dim3(NHEAD/4,SEQ,BATCH), blk, 0, stream>>>(P2, Kb, fc, fs, sqk);
  k_vt<<<dim3(SEQ/64,NHEAD,BATCH), blk, 0, stream>>>(Vb, Vt);
  k_flash_mf<<<dim3(SEQ/64,NHEAD,BATCH), blk, 0, stream>>>(P2, Kb, Vt, P1);
  k_gemm_mf<128,64,ushort_t><<<dim3(16,32), blk, 0, stream>>>(P1, woT, Vb, DIMN, DIMN);
  k_rn<float,ushort_t,ushort_t><<<dim3(ROWS), blk, 0, stream>>>(x, Vb, aal, P2);

  // FFN branch
  k_modulate<ushort_t><<<dim3(64,128,BATCH), blk, 0, stream>>>(P2, g + 512, P1);
  for(int c2 = 0; c2 < ROWS/FCHUNK; c2++){
    const ushort_t* Ac = P1 + (size_t)c2*FCHUNK*DIMN;
    k_gemm_mf<128,64,ushort_t><<<dim3(HIDDEN/64,FCHUNK/128), blk, 0, stream>>>(Ac, w1T, a1c, HIDDEN, DIMN);
    k_gemm_mf<128,64,ushort_t><<<dim3(HIDDEN/64,FCHUNK/128), blk, 0, stream>>>(Ac, w3T, a3c, HIDDEN, DIMN);
    k_ffnew<<<dim3(FCHUNK*HIDDEN/256), blk, 0, stream>>>(a1c, a3c, su, sv);
    k_gemm_mf<64,64,ushort_t><<<dim3(16,FCHUNK/64), blk, 0, stream>>>(a1c, w2T, Kb + (size_t)c2*FCHUNK*DIMN, DIMN, HIDDEN);
  }

  k_rn<ushort_t,ushort_t,float><<<dim3(ROWS), blk, 0, stream>>>(P2, Kb, mal, out);
}

// Round 6
// 547.929 us; speedup vs baseline: 9.4119x; 1.6169x over previous
//
#include <hip/hip_runtime.h>
#include <hip/hip_bf16.h>
#include <math.h>

#define SEQ    2048
#define DIMN   1024
#define NHEAD  16
#define HDIM   64
#define BATCH  2
#define ROWS   4096
#define HIDDEN 2816
#define FCHUNK 2048

typedef __attribute__((ext_vector_type(8))) short short8;
typedef __attribute__((ext_vector_type(4))) float f32x4;
typedef unsigned short ushort_t;
typedef __attribute__((address_space(1))) void gas_t;
typedef __attribute__((address_space(3))) void las_t;

__device__ __forceinline__ float bfbits(ushort_t u){ return __uint_as_float(((unsigned)u) << 16); }
__device__ __forceinline__ ushort_t f2bu(float f){
  __hip_bfloat16 h = __float2bfloat16(f);
  return *reinterpret_cast<ushort_t*>(&h);
}
__device__ __forceinline__ float ldv(const float* p){ return *p; }
__device__ __forceinline__ float ldv(const ushort_t* p){ return bfbits(*p); }
__device__ __forceinline__ void stv(float* p, float v){ *p = v; }
__device__ __forceinline__ void stv(ushort_t* p, float v){ *p = f2bu(v); }
__device__ __forceinline__ void async_cp16(const ushort_t* g, ushort_t* l){
  __builtin_amdgcn_global_load_lds((gas_t*)g, (las_t*)l, 16, 0, 0);
}
__device__ __forceinline__ ushort4 ld4u(const float* p){
  float4 v = *(const float4*)p;
  ushort4 u; u.x = f2bu(v.x); u.y = f2bu(v.y); u.z = f2bu(v.z); u.w = f2bu(v.w);
  return u;
}
__device__ __forceinline__ ushort4 ld4u(const ushort_t* p){ return *(const ushort4*)p; }

// ---------------- t = silu(adafm_input) @ proj_w + proj_b ----------------
__global__ void k_time(const float* __restrict__ ada, const float* __restrict__ pw,
                       const float* __restrict__ pb, float* __restrict__ t){
  int b = blockIdx.x >> 9, o = blockIdx.x & 511, lane = threadIdx.x;
  float acc = 0.f;
  for(int i = lane; i < DIMN; i += 64){
    float a = ada[b*DIMN + i];
    float s = a / (1.f + expf(-a));
    acc += s * pw[i*512 + o];
  }
  for(int off = 32; off; off >>= 1) acc += __shfl_down(acc, off);
  if(lane == 0) t[b*512 + o] = acc + pb[o];
}

// ---------------- g[wb][n] = (1/256) sum_k F[k] cos(2*pi*k*n/256) ----------------
__global__ void k_g(const float* __restrict__ t, float* __restrict__ g){
  int which = blockIdx.x >> 1, b = blockIdx.x & 1, n = threadIdx.x;
  const float C = 6.283185307179586f / 256.f;
  float acc = 0.f;
  for(int k = 0; k < 256; k++){
    float f = t[b*512 + which*256 + k];
    acc += f * cosf(C * (float)((k*n) & 255));
  }
  g[(which*2 + b)*256 + n] = acc * (1.f/256.f);
}

// ---------------- pack circulant: Gpk[wb][kc][n][mm] = g_wb[(n - kc*32 - mm)&255] ----------------
__global__ void k_gpack(const float* __restrict__ g, ushort_t* __restrict__ Gpk){
  int wb = blockIdx.x, kc = blockIdx.y, tid = threadIdx.x;
  const float* gb = g + wb*256;
  ushort_t* ob = Gpk + ((size_t)(wb*8 + kc))*8192;
  for(int rep = 0; rep < 4; rep++){
    int n = rep*64 + (tid >> 2), mmb = (tid & 3)*8;
    short8 o;
    #pragma unroll
    for(int j = 0; j < 8; j++)
      o[j] = (short)f2bu(gb[(n - kc*32 - (mmb + j)) & 255]);
    *(short8*)(ob + n*32 + mmb) = o;
  }
}

// ---------------- MFMA modulate: per-patch circular conv as GEMM ----------------
// grid (2, 128, B). Block: 64 patches (M) x 128 n (N-half) x K=256.
#define APAD 264
#define GPAD 40
template<typename IN>
__global__ __launch_bounds__(256) void k_modmf(const IN* __restrict__ src,
        const ushort_t* __restrict__ Gpk, ushort_t* __restrict__ dst){
  __shared__ __align__(16) ushort_t Ap[64*APAD];
  __shared__ __align__(16) ushort_t Gs[128*GPAD];
  int nh = blockIdx.x, i = blockIdx.y, b = blockIdx.z;
  int tid = threadIdx.x, lane = tid & 63, w = tid >> 6;
  int l15 = lane & 15, quad = lane >> 4;
  // stage Ap[patch j][m = r*16+c] from 16 rows x 1024 cols
  const IN* xb = src + (size_t)b*SEQ*DIMN + (size_t)(i*16)*DIMN;
  int j = tid >> 2, c = (tid & 3)*4;
  #pragma unroll 4
  for(int rep = 0; rep < 16; rep++){
    ushort4 v4 = ld4u(xb + (size_t)rep*DIMN + tid*4);
    *(ushort4*)&Ap[j*APAD + rep*16 + c] = v4;
  }
  f32x4 acc[8];
  #pragma unroll
  for(int nt = 0; nt < 8; nt++){ acc[nt][0]=0.f; acc[nt][1]=0.f; acc[nt][2]=0.f; acc[nt][3]=0.f; }
  for(int kc = 0; kc < 8; kc++){
    __syncthreads();
    {
      const ushort_t* gsrc = Gpk + ((size_t)(b*8 + kc))*8192 + nh*4096;
      #pragma unroll
      for(int r2 = 0; r2 < 2; r2++){
        int idx = r2*2048 + tid*8;
        int n = r2*64 + (tid >> 2), mm = (tid & 3)*8;
        *(short8*)&Gs[n*GPAD + mm] = *(const short8*)(gsrc + idx);
      }
    }
    __syncthreads();
    short8 af = *(const short8*)&Ap[(w*16 + l15)*APAD + kc*32 + quad*8];
    #pragma unroll
    for(int nt = 0; nt < 8; nt++){
      short8 bf = *(const short8*)&Gs[(nt*16 + l15)*GPAD + quad*8];
      acc[nt] = __builtin_amdgcn_mfma_f32_16x16x32_bf16(af, bf, acc[nt], 0, 0, 0);
    }
  }
  size_t ob = (size_t)b*SEQ*DIMN + (size_t)(i*16 + nh*8)*DIMN + (w*16 + quad*4)*16 + l15;
  #pragma unroll
  for(int nt = 0; nt < 8; nt++)
    #pragma unroll
    for(int t = 0; t < 4; t++)
      dst[ob + (size_t)nt*DIMN + t*16] = f2bu(acc[nt][t]);
}

// ---------------- weight transpose: fp32 W[K][N] -> bf16 Wt[N][K] ----------------
__global__ void k_wt(const float* __restrict__ W, ushort_t* __restrict__ Wt, int K, int N){
  __shared__ float tile[32][33];
  int k0 = blockIdx.y*32, n0 = blockIdx.x*32;
  int r = threadIdx.x >> 3, c4 = (threadIdx.x & 7)*4;
  float4 v = *(const float4*)(W + (size_t)(k0 + r)*N + n0 + c4);
  tile[r][c4+0] = v.x; tile[r][c4+1] = v.y; tile[r][c4+2] = v.z; tile[r][c4+3] = v.w;
  __syncthreads();
  ushort4 o;
  o.x = f2bu(tile[c4+0][r]); o.y = f2bu(tile[c4+1][r]);
  o.z = f2bu(tile[c4+2][r]); o.w = f2bu(tile[c4+3][r]);
  *(ushort4*)(Wt + (size_t)(n0 + r)*K + k0 + c4) = o;
}

// ---------------- m97-style MFMA GEMM: C(MxN) = A(MxK) @ Wt(NxK)^T ----------------
template<int BM, int BN, typename OUT>
__global__ __launch_bounds__(256) void k_gemm_mf(const ushort_t* __restrict__ A,
        const ushort_t* __restrict__ Wt, OUT* __restrict__ C, int N, int K){
  constexpr int MT = BM/32, NT = BN/32;
  constexpr int AI = BM/64, BI = BN/64;
  __shared__ __align__(16) ushort_t As[BM*32];
  __shared__ __align__(16) ushort_t Bs[BN*32];
  int tid = threadIdx.x, lane = tid & 63, w = tid >> 6;
  int l15 = lane & 15, quad = lane >> 4;
  int m0 = blockIdx.y*BM, n0 = blockIdx.x*BN;
  int wr = (w>>1)*(BM/2), wc = (w&1)*(BN/2);
  int srow = lane >> 2, scol = (lane & 3)*8;
  const ushort_t* ag[AI]; ushort_t* al[AI];
  const ushort_t* bg[BI]; ushort_t* bl[BI];
  #pragma unroll
  for(int i = 0; i < AI; i++){
    int rb = w*AI + i;
    ag[i] = A + (size_t)(m0 + rb*16 + srow)*K + scol;
    al[i] = As + rb*512 + lane*8;
  }
  #pragma unroll
  for(int i = 0; i < BI; i++){
    int rb = w*BI + i;
    bg[i] = Wt + (size_t)(n0 + rb*16 + srow)*K + scol;
    bl[i] = Bs + rb*512 + lane*8;
  }
  f32x4 acc[MT][NT];
  #pragma unroll
  for(int mt = 0; mt < MT; mt++)
    #pragma unroll
    for(int nt = 0; nt < NT; nt++)
      for(int t = 0; t < 4; t++) acc[mt][nt][t] = 0.f;
  for(int kk = 0; kk < K; kk += 32){
    __syncthreads();
    #pragma unroll
    for(int i = 0; i < AI; i++) async_cp16(ag[i] + kk, al[i]);
    #pragma unroll
    for(int i = 0; i < BI; i++) async_cp16(bg[i] + kk, bl[i]);
    __syncthreads();
    short8 af[MT], bf[NT];
    #pragma unroll
    for(int mt = 0; mt < MT; mt++) af[mt] = *(const short8*)&As[(wr + mt*16 + l15)*32 + quad*8];
    #pragma unroll
    for(int nt = 0; nt < NT; nt++) bf[nt] = *(const short8*)&Bs[(wc + nt*16 + l15)*32 + quad*8];
    #pragma unroll
    for(int mt = 0; mt < MT; mt++)
      #pragma unroll
      for(int nt = 0; nt < NT; nt++)
        acc[mt][nt] = __builtin_amdgcn_mfma_f32_16x16x32_bf16(af[mt], bf[nt], acc[mt][nt], 0, 0, 0);
  }
  #pragma unroll
  for(int mt = 0; mt < MT; mt++)
    #pragma unroll
    for(int nt = 0; nt < NT; nt++)
      #pragma unroll
      for(int t = 0; t < 4; t++)
        stv(C + (size_t)(m0 + wr + mt*16 + quad*4 + t)*N + n0 + wc + nt*16 + l15, acc[mt][nt][t]);
}

// ---------------- fused FFN up: h = silu(A@w1 * sv*sqrt(H)) * (A@w3 * su) ----------------
// BM=128, BN=64, dual B staging, bf16 output [M][HIDDEN].
__global__ __launch_bounds__(256) void k_ffn12(const ushort_t* __restrict__ A,
        const ushort_t* __restrict__ W1t, const ushort_t* __restrict__ W3t,
        const float* __restrict__ su, const float* __restrict__ sv,
        ushort_t* __restrict__ H, int K){
  __shared__ __align__(16) ushort_t As[128*32];
  __shared__ __align__(16) ushort_t B1s[64*32];
  __shared__ __align__(16) ushort_t B3s[64*32];
  int tid = threadIdx.x, lane = tid & 63, w = tid >> 6;
  int l15 = lane & 15, quad = lane >> 4;
  int m0 = blockIdx.y*128, n0 = blockIdx.x*64;
  int wr = (w>>1)*64, wc = (w&1)*32;
  int srow = lane >> 2, scol = (lane & 3)*8;
  const ushort_t* ag[2]; ushort_t* al[2];
  #pragma unroll
  for(int i = 0; i < 2; i++){
    int rb = w*2 + i;
    ag[i] = A + (size_t)(m0 + rb*16 + srow)*K + scol;
    al[i] = As + rb*512 + lane*8;
  }
  const ushort_t* b1g = W1t + (size_t)(n0 + w*16 + srow)*K + scol;
  const ushort_t* b3g = W3t + (size_t)(n0 + w*16 + srow)*K + scol;
  ushort_t* b1l = B1s + w*512 + lane*8;
  ushort_t* b3l = B3s + w*512 + lane*8;
  f32x4 acc1[4][2], acc3[4][2];
  #pragma unroll
  for(int mt = 0; mt < 4; mt++)
    #pragma unroll
    for(int nt = 0; nt < 2; nt++)
      for(int t = 0; t < 4; t++){ acc1[mt][nt][t] = 0.f; acc3[mt][nt][t] = 0.f; }
  for(int kk = 0; kk < K; kk += 32){
    __syncthreads();
    async_cp16(ag[0] + kk, al[0]);
    async_cp16(ag[1] + kk, al[1]);
    async_cp16(b1g + kk, b1l);
    async_cp16(b3g + kk, b3l);
    __syncthreads();
    short8 af[4], b1f[2], b3f[2];
    #pragma unroll
    for(int mt = 0; mt < 4; mt++) af[mt] = *(const short8*)&As[(wr + mt*16 + l15)*32 + quad*8];
    #pragma unroll
    for(int nt = 0; nt < 2; nt++){
      b1f[nt] = *(const short8*)&B1s[(wc + nt*16 + l15)*32 + quad*8];
      b3f[nt] = *(const short8*)&B3s[(wc + nt*16 + l15)*32 + quad*8];
    }
    #pragma unroll
    for(int mt = 0; mt < 4; mt++)
      #pragma unroll
      for(int nt = 0; nt < 2; nt++){
        acc1[mt][nt] = __builtin_amdgcn_mfma_f32_16x16x32_bf16(af[mt], b1f[nt], acc1[mt][nt], 0, 0, 0);
        acc3[mt][nt] = __builtin_amdgcn_mfma_f32_16x16x32_bf16(af[mt], b3f[nt], acc3[mt][nt], 0, 0, 0);
      }
  }
  #pragma unroll
  for(int nt = 0; nt < 2; nt++){
    int n = n0 + wc + nt*16 + l15;
    float svv = sv[n] * 53.06599665f, suv = su[n];
    #pragma unroll
    for(int mt = 0; mt < 4; mt++)
      #pragma unroll
      for(int t = 0; t < 4; t++){
        float hpre = acc1[mt][nt][t] * svv;
        float sil = hpre / (1.f + expf(-hpre));
        float hv = sil * (acc3[mt][nt][t] * suv);
        H[(size_t)(m0 + wr + mt*16 + quad*4 + t)*HIDDEN + n] = f2bu(hv);
      }
  }
}

// ---------------- rotary + justnorm + sqk scale, in place, 4 heads/block ----------------
__global__ void k_qkvprep(ushort_t* __restrict__ xq, ushort_t* __restrict__ xk,
        const float* __restrict__ fc, const float* __restrict__ fs,
        const float* __restrict__ sqk){
  int w = threadIdx.x >> 6, d = threadIdx.x & 63;
  int h = blockIdx.x*4 + w, s = blockIdx.y, b = blockIdx.z;
  size_t ib = ((size_t)(b*SEQ + s))*DIMN + h*HDIM + d;
  float q = bfbits(xq[ib]), k = bfbits(xk[ib]);
  float qn = __shfl_xor(q, 1), kn = __shfl_xor(k, 1);
  int p = d >> 1;
  float c = fc[s*32 + p], sn = fs[s*32 + p];
  float qr, kr;
  if((d & 1) == 0){ qr = q*c - qn*sn; kr = k*c - kn*sn; }
  else            { qr = qn*sn + q*c; kr = kn*sn + k*c; }
  float sq = qr*qr, sk = kr*kr;
  for(int off = 32; off; off >>= 1){ sq += __shfl_xor(sq, off); sk += __shfl_xor(sk, off); }
  float scl = sqk[h*HDIM + d] * 32.f;
  xq[ib] = f2bu(scl * qr / fmaxf(sqrtf(sq), 1e-12f));
  xk[ib] = f2bu(scl * kr / fmaxf(sqrtf(sk), 1e-12f));
}

// ---------------- V transpose to [b][h][d][s] ----------------
__global__ void k_vt(const ushort_t* __restrict__ v, ushort_t* __restrict__ vto){
  __shared__ ushort_t tile[64][72];
  int s0 = blockIdx.x*64, h = blockIdx.y, b = blockIdx.z;
  int r = threadIdx.x >> 2, c = (threadIdx.x & 3)*16;
  const ushort_t* src = v + (size_t)(b*SEQ + s0 + r)*DIMN + h*HDIM + c;
  *(short8*)&tile[r][c]     = *(const short8*)src;
  *(short8*)&tile[r][c + 8] = *(const short8*)(src + 8);
  __syncthreads();
  ushort_t* dst = vto + ((size_t)(b*NHEAD + h)*HDIM + r)*SEQ + s0 + c;
  for(int j = 0; j < 16; j += 4){
    ushort4 o;
    o.x = tile[c+j][r]; o.y = tile[c+j+1][r]; o.z = tile[c+j+2][r]; o.w = tile[c+j+3][r];
    *(ushort4*)(dst + j) = o;
  }
}

// ---------------- MFMA flash attention, fixed-max softmax ----------------
#define LSTR 72
__global__ __launch_bounds__(256) void k_flash_mf(const ushort_t* __restrict__ qp,
        const ushort_t* __restrict__ kp, const ushort_t* __restrict__ vt,
        ushort_t* __restrict__ out){
  int qb = blockIdx.x, h = blockIdx.y, b = blockIdx.z;
  int tid = threadIdx.x, lane = tid & 63, w = tid >> 6;
  int l15 = lane & 15, quad = lane >> 4;
  __shared__ __align__(16) ushort_t Ks[64*LSTR], Vts[64*LSTR];
  __shared__ __align__(16) ushort_t Ps[4][16*LSTR];
  size_t hb = (size_t)b*SEQ*DIMN + h*HDIM;
  const ushort_t* vb = vt + (size_t)(b*NHEAD + h)*HDIM*SEQ;
  short8 qf0, qf1;
  {
    const ushort_t* qrow = qp + hb + (size_t)(qb*64 + w*16 + l15)*DIMN;
    qf0 = *(const short8*)(qrow + quad*8);
    qf1 = *(const short8*)(qrow + 32 + quad*8);
  }
  f32x4 o_acc[4];
  #pragma unroll
  for(int g = 0; g < 4; g++) for(int t = 0; t < 4; t++) o_acc[g][t] = 0.f;
  float lsum = 0.f;
  int sr = tid >> 2, sc = tid & 3;
  const float C1 = 11.54156036f;
  const float C2 = 11.90223409f;
  for(int ch = 0; ch < SEQ/64; ch++){
    __syncthreads();
    {
      const ushort_t* krow = kp + hb + (size_t)(ch*64 + sr)*DIMN + sc*16;
      short8 k0 = *(const short8*)krow, k1 = *(const short8*)(krow + 8);
      const ushort_t* vrow = vb + (size_t)sr*SEQ + ch*64 + sc*16;
      short8 v0 = *(const short8*)vrow, v1 = *(const short8*)(vrow + 8);
      *(short8*)&Ks[sr*LSTR + sc*16]      = k0;
      *(short8*)&Ks[sr*LSTR + sc*16 + 8]  = k1;
      *(short8*)&Vts[sr*LSTR + sc*16]     = v0;
      *(short8*)&Vts[sr*LSTR + sc*16 + 8] = v1;
    }
    __syncthreads();
    #pragma unroll
    for(int g = 0; g < 4; g++){
      f32x4 sa; sa[0] = 0.f; sa[1] = 0.f; sa[2] = 0.f; sa[3] = 0.f;
      short8 k0 = *(const short8*)&Ks[(g*16 + l15)*LSTR + quad*8];
      short8 k1 = *(const short8*)&Ks[(g*16 + l15)*LSTR + 32 + quad*8];
      sa = __builtin_amdgcn_mfma_f32_16x16x32_bf16(k0, qf0, sa, 0, 0, 0);
      sa = __builtin_amdgcn_mfma_f32_16x16x32_bf16(k1, qf1, sa, 0, 0, 0);
      float e0 = exp2f(fmaf(sa[0], C1, -C2));
      float e1 = exp2f(fmaf(sa[1], C1, -C2));
      float e2 = exp2f(fmaf(sa[2], C1, -C2));
      float e3 = exp2f(fmaf(sa[3], C1, -C2));
      lsum += (e0 + e1) + (e2 + e3);
      ushort4 pk;
      pk.x = f2bu(e0); pk.y = f2bu(e1); pk.z = f2bu(e2); pk.w = f2bu(e3);
      *(ushort4*)&Ps[w][l15*LSTR + g*16 + quad*4] = pk;
    }
    short8 a0 = *(const short8*)&Ps[w][l15*LSTR + quad*8];
    short8 a1 = *(const short8*)&Ps[w][l15*LSTR + 32 + quad*8];
    #pragma unroll
    for(int g = 0; g < 4; g++){
      short8 b0 = *(const short8*)&Vts[(g*16 + l15)*LSTR + quad*8];
      short8 b1 = *(const short8*)&Vts[(g*16 + l15)*LSTR + 32 + quad*8];
      o_acc[g] = __builtin_amdgcn_mfma_f32_16x16x32_bf16(a0, b0, o_acc[g], 0, 0, 0);
      o_acc[g] = __builtin_amdgcn_mfma_f32_16x16x32_bf16(a1, b1, o_acc[g], 0, 0, 0);
    }
  }
  lsum += __shfl_xor(lsum, 16);
  lsum += __shfl_xor(lsum, 32);
  #pragma unroll
  for(int t = 0; t < 4; t++){
    float lr = __shfl(lsum, quad*4 + t);
    float inv = 1.f / lr;
    #pragma unroll
    for(int g = 0; g < 4; g++)
      out[hb + (size_t)(qb*64 + w*16 + quad*4 + t)*DIMN + g*16 + l15] = f2bu(o_acc[g][t] * inv);
  }
}

// ---------------- block reduce helper ----------------
__device__ __forceinline__ float blockReduceSum(float v, float* red){
  for(int off = 32; off; off >>= 1) v += __shfl_xor(v, off);
  int wid = threadIdx.x >> 6;
  if((threadIdx.x & 63) == 0) red[wid] = v;
  __syncthreads();
  float tot = red[0] + red[1] + red[2] + red[3];
  __syncthreads();
  return tot;
}

// ---------------- xo = justnorm(h + lr*(justnorm(ha) - h)), h = justnorm(x) ----------------
template<typename T1, typename T2, typename TO>
__global__ void k_rn(const T1* __restrict__ x, const T2* __restrict__ ha,
        const float* __restrict__ alpha, TO* __restrict__ xo){
  __shared__ float red[4];
  int row = blockIdx.x, tid = threadIdx.x;
  size_t base = (size_t)row * DIMN;
  float xs[4], hs[4], cs[4];
  float s1 = 0.f, s2 = 0.f;
  for(int j = 0; j < 4; j++){
    int i = tid + j*256;
    float xv = ldv(x + base + i);  xs[j] = xv; s1 += xv*xv;
    float hv = ldv(ha + base + i); hs[j] = hv; s2 += hv*hv;
  }
  s1 = blockReduceSum(s1, red);
  s2 = blockReduceSum(s2, red);
  float r1 = 1.f / fmaxf(sqrtf(s1), 1e-12f);
  float r2 = 1.f / fmaxf(sqrtf(s2), 1e-12f);
  float s3 = 0.f;
  for(int j = 0; j < 4; j++){
    int i = tid + j*256;
    float lr = fabsf(alpha[i] * 1.6f);
    float hn = xs[j] * r1;
    float cv = hn + lr*(hs[j]*r2 - hn);
    cs[j] = cv; s3 += cv*cv;
  }
  s3 = blockReduceSum(s3, red);
  float r3 = 1.f / fmaxf(sqrtf(s3), 1e-12f);
  for(int j = 0; j < 4; j++){
    int i = tid + j*256;
    stv(xo + base + i, cs[j] * r3);
  }
}

extern "C" void kernel_launch(void* const* d_in, const int* in_sizes, int n_in,
                              void* d_out, int out_size, void* d_ws, size_t ws_size,
                              hipStream_t stream){
  const float* x   = (const float*)d_in[0];
  const float* fc  = (const float*)d_in[1];
  const float* fs  = (const float*)d_in[2];
  const float* ada = (const float*)d_in[3];
  const float* wq  = (const float*)d_in[4];
  const float* wk  = (const float*)d_in[5];
  const float* wv  = (const float*)d_in[6];
  const float* wo  = (const float*)d_in[7];
  const float* sqk = (const float*)d_in[8];
  const float* w1  = (const float*)d_in[9];
  const float* w2  = (const float*)d_in[10];
  const float* w3  = (const float*)d_in[11];
  const float* su  = (const float*)d_in[12];
  const float* sv  = (const float*)d_in[13];
  const float* pw  = (const float*)d_in[14];
  const float* pb  = (const float*)d_in[15];
  const float* aal = (const float*)d_in[16];
  const float* mal = (const float*)d_in[17];
  float* out = (float*)d_out;

  const size_t MM = (size_t)DIMN*DIMN;
  const size_t HM = (size_t)HIDDEN*DIMN;
  const size_t F  = (size_t)ROWS*DIMN;
  char* wsb = (char*)d_ws;
  float* t = (float*)wsb;                      // 1024
  float* g = t + 1024;                         // 1024 (4 x 256)
  ushort_t* Gpk = (ushort_t*)(wsb + 16384);    // 4*8*8192 = 262144 el
  ushort_t* wqT = Gpk + 262144;
  ushort_t* wkT = wqT + MM;
  ushort_t* wvT = wkT + MM;
  ushort_t* woT = wvT + MM;
  ushort_t* w1T = woT + MM;                    // [2816][1024]
  ushort_t* w3T = w1T + HM;
  ushort_t* w2T = w3T + HM;                    // [1024][2816]
  ushort_t* P1  = w2T + HM;                    // xmod -> attnO -> xmod2
  ushort_t* P2  = P1 + F;                      // q -> x1
  ushort_t* Kb  = P2 + F;                      // k -> h_m
  ushort_t* Vb  = Kb + F;                      // v -> h_a
  ushort_t* a1  = Vb + F;                      // [FCHUNK][HIDDEN] = 5.77M el; aliases Vt
  ushort_t* Vt  = a1;                          // [B][NH][64][SEQ] = 4M el

  dim3 blk(256);

  k_time<<<dim3(1024), dim3(64), 0, stream>>>(ada, pw, pb, t);
  k_g<<<dim3(4), blk, 0, stream>>>(t, g);
  k_gpack<<<dim3(4,8), blk, 0, stream>>>(g, Gpk);

  k_wt<<<dim3(32,32), blk, 0, stream>>>(wq, wqT, DIMN, DIMN);
  k_wt<<<dim3(32,32), blk, 0, stream>>>(wk, wkT, DIMN, DIMN);
  k_wt<<<dim3(32,32), blk, 0, stream>>>(wv, wvT, DIMN, DIMN);
  k_wt<<<dim3(32,32), blk, 0, stream>>>(wo, woT, DIMN, DIMN);
  k_wt<<<dim3(HIDDEN/32,32), blk, 0, stream>>>(w1, w1T, DIMN, HIDDEN);
  k_wt<<<dim3(HIDDEN/32,32), blk, 0, stream>>>(w3, w3T, DIMN, HIDDEN);
  k_wt<<<dim3(32,HIDDEN/32), blk, 0, stream>>>(w2, w2T, HIDDEN, DIMN);

  // attention branch
  k_modmf<float><<<dim3(2,128,BATCH), blk, 0, stream>>>(x, Gpk, P1);
  k_gemm_mf<128,64,ushort_t><<<dim3(16,32), blk, 0, stream>>>(P1, wqT, P2, DIMN, DIMN);
  k_gemm_mf<128,64,ushort_t><<<dim3(16,32), blk, 0, stream>>>(P1, wkT, Kb, DIMN, DIMN);
  k_gemm_mf<128,64,ushort_t><<<dim3(16,32), blk, 0, stream>>>(P1, wvT, Vb, DIMN, DIMN);
  k_qkvprep<<<dim3(NHEAD/4,SEQ,BATCH), blk, 0, stream>>>(P2, Kb, fc, fs, sqk);
  k_vt<<<dim3(SEQ/64,NHEAD,BATCH), blk, 0, stream>>>(Vb, Vt);
  k_flash_mf<<<dim3(SEQ/64,NHEAD,BATCH), blk, 0, stream>>>(P2, Kb, Vt, P1);
  k_gemm_mf<128,64,ushort_t><<<dim3(16,32), blk, 0, stream>>>(P1, woT, Vb, DIMN, DIMN);
  k_rn<float,ushort_t,ushort_t><<<dim3(ROWS), blk, 0, stream>>>(x, Vb, aal, P2);

  // FFN branch
  k_modmf<ushort_t><<<dim3(2,128,BATCH), blk, 0, stream>>>(P2, Gpk + 131072, P1);
  for(int c2 = 0; c2 < ROWS/FCHUNK; c2++){
    const ushort_t* Ac = P1 + (size_t)c2*FCHUNK*DIMN;
    k_ffn12<<<dim3(HIDDEN/64,FCHUNK/128), blk, 0, stream>>>(Ac, w1T, w3T, su, sv, a1, DIMN);
    k_gemm_mf<64,64,ushort_t><<<dim3(16,FCHUNK/64), blk, 0, stream>>>(a1, w2T, Kb + (size_t)c2*FCHUNK*DIMN, DIMN, HIDDEN);
  }

  k_rn<ushort_t,ushort_t,float><<<dim3(ROWS), blk, 0, stream>>>(P2, Kb, mal, out);
}